// Round 12
// baseline (968.001 us; speedup 1.0000x reference)
//
#include <hip/hip_runtime.h>

#define HID   24
#define T_LEN 4096
#define BATCH 1024
#define NBB   4                  // batches per block (2 per lane, one pair per 32-lane half)
#define K     16                 // timesteps per chunk (pipeline skew per layer)
#define NC    (T_LEN / K)        // 256 active chunks per layer
#define CTOT  (NC + 2)           // 258 ticks total
#define TPB   192                // 3 waves: wave w == layer w; 1 block/CU -> 1 wave/SIMD

typedef __attribute__((ext_vector_type(2))) _Float16 h2v;
typedef __attribute__((ext_vector_type(4))) int      int4v;
typedef __attribute__((ext_vector_type(2))) unsigned int uint2v;

#if __has_builtin(__builtin_amdgcn_fdot2)
__device__ __forceinline__ float dot2f(int p, int w, float acc) {
    return __builtin_amdgcn_fdot2(__builtin_bit_cast(h2v, p),
                                  __builtin_bit_cast(h2v, w), acc, false);
}
#else
__device__ __forceinline__ float dot2f(int p, int w, float acc) {
    h2v a = __builtin_bit_cast(h2v, p), b = __builtin_bit_cast(h2v, w);
    acc = fmaf((float)a.x, (float)b.x, acc);
    return fmaf((float)a.y, (float)b.y, acc);
}
#endif

__device__ __forceinline__ float dot4(const float4 a, const float4 b, float acc) {
    acc = fmaf(a.x, b.x, acc);
    acc = fmaf(a.y, b.y, acc);
    acc = fmaf(a.z, b.z, acc);
    return fmaf(a.w, b.w, acc);
}

template<int N> __device__ __forceinline__ int rr(int v) {
    return __builtin_amdgcn_mov_dpp(v, 0x120 + N, 0xF, 0xF, false);
}
__device__ __forceinline__ int qp_nbr(int v) {
    return __builtin_amdgcn_mov_dpp(v, 0xB1, 0xF, 0xF, false);
}

#define PKF(A_, B_)                                                                 \
    (((int)__builtin_bit_cast(unsigned short, (_Float16)(B_)) << 16) |              \
     (int)__builtin_bit_cast(unsigned short, (_Float16)(A_)))

__device__ __forceinline__ int pkw(const float* row, int m, int par) {
    float wl = row[2 * m], wh = row[2 * m + 1];
    if (par) { float t = wl; wl = wh; wh = t; }
    const unsigned short ul = __builtin_bit_cast(unsigned short, (_Float16)wl);
    const unsigned short uh = __builtin_bit_cast(unsigned short, (_Float16)wh);
    return ((int)uh << 16) | (int)ul;
}

template<bool USE_BP>
__device__ __forceinline__ void run_rnn(
    const float* __restrict__ x, const float* __restrict__ h_in,
    const float* __restrict__ Wih0, const float* __restrict__ bih0,
    const float* __restrict__ Whh0, const float* __restrict__ bhh0,
    const float* __restrict__ Wih1, const float* __restrict__ bih1,
    const float* __restrict__ Whh1, const float* __restrict__ bhh1,
    const float* __restrict__ Wih2, const float* __restrict__ bih2,
    const float* __restrict__ Whh2, const float* __restrict__ bhh2,
    const float* __restrict__ W1,   const float* __restrict__ b1,
    const float* __restrict__ W2,   const float* __restrict__ b2,
    float* __restrict__ out, const int dir, const bool flip,
    _Float16* pub0, _Float16* pub1, float (*h2f)[HID], float (*mbuf)[HID])
{
    const int tid  = threadIdx.x;
    const int l    = tid >> 6;        // wave == layer
    const int lane = tid & 63;
    const int bl   = lane >> 5;       // half -> batch pair
    const int jj   = lane & 31;
    const bool act = (jj < HID);
    const int uL   = act ? jj : (jj - 8);
    const int par  = lane & 1;
    const int bgA  = blockIdx.x * NBB + bl * 2;
    const int bgB  = bgA + 1;
    const int alo  = (((lane & 32) | (lane & 15)) << 2);
    const int ahi  = (((lane & 32) | 16 | (lane & 15)) << 2);

    // own-h weights permuted to the DPP gather order
    int wP[12];
    {
        const float* ownrow = ((l == 0) ? Whh0 : (l == 1) ? Whh1 : Whh2) + uL * HID;
        #pragma unroll
        for (int k = 0; k < 12; ++k) {
            const int r = (k < 8) ? (2 * k) : (2 * (k - 8));
            const int s = (((lane & 15) + dir * r) & 15);
            const int m = (k < 8) ? (s >> 1) : (8 + ((s >> 1) & 3));
            wP[k] = pkw(ownrow, m, par);
        }
    }
    int4v wiA_ = {0,0,0,0}, wiB_ = {0,0,0,0}, wiC_ = {0,0,0,0};
    if (l >= 1) {
        const float* r_ = ((l == 1) ? Wih1 : Wih2) + uL * HID;
        wiA_ = (int4v){PKF(r_[0], r_[1]),   PKF(r_[2], r_[3]),
                       PKF(r_[4], r_[5]),   PKF(r_[6], r_[7])};
        wiB_ = (int4v){PKF(r_[8], r_[9]),   PKF(r_[10], r_[11]),
                       PKF(r_[12], r_[13]), PKF(r_[14], r_[15])};
        wiC_ = (int4v){PKF(r_[16], r_[17]), PKF(r_[18], r_[19]),
                       PKF(r_[20], r_[21]), PKF(r_[22], r_[23])};
    }
    const float wx0  = Wih0[uL];
    const float bias = (l == 0) ? (bih0[uL] + bhh0[uL])
                     : (l == 1) ? (bih1[uL] + bhh1[uL])
                                : (bih2[uL] + bhh2[uL]);

    float curA = h_in[(l * BATCH + bgA) * HID + uL];
    float curB = h_in[(l * BATCH + bgB) * HID + uL];

#define GATHER(CF_, R_) do {                                                        \
    int hc_ = (int)(unsigned)__builtin_bit_cast(unsigned short, (_Float16)(CF_));   \
    int pk_ = (qp_nbr(hc_) << 16) | hc_;                                            \
    int ea_, eb_;                                                                   \
    if constexpr (USE_BP) {                                                         \
        ea_ = __builtin_amdgcn_ds_bpermute(alo, pk_);                               \
        eb_ = __builtin_amdgcn_ds_bpermute(ahi, pk_);                               \
    } else {                                                                        \
        uint2v s_ = __builtin_amdgcn_permlane16_swap((unsigned)pk_, (unsigned)pk_,  \
                                                     false, false);                 \
        ea_ = flip ? (int)s_.y : (int)s_.x;                                         \
        eb_ = flip ? (int)s_.x : (int)s_.y;                                         \
    }                                                                               \
    R_[0] = ea_;         R_[1] = rr<2>(ea_);   R_[2] = rr<4>(ea_);                  \
    R_[3] = rr<6>(ea_);  R_[4] = rr<8>(ea_);   R_[5] = rr<10>(ea_);                 \
    R_[6] = rr<12>(ea_); R_[7] = rr<14>(ea_);                                       \
    R_[8] = eb_;         R_[9] = rr<2>(eb_);   R_[10] = rr<4>(eb_);                 \
    R_[11] = rr<6>(eb_);                                                            \
} while (0)

// dual interleaved own-dots (both batch streams alternate line-by-line)
#define DOT12P2(RA_, RB_, W_, A0A_, A1A_, A0B_, A1B_)                               \
    A0A_ = dot2f(RA_[0], W_[0], A0A_);   A0B_ = dot2f(RB_[0], W_[0], A0B_);         \
    A1A_ = dot2f(RA_[1], W_[1], A1A_);   A1B_ = dot2f(RB_[1], W_[1], A1B_);         \
    A0A_ = dot2f(RA_[2], W_[2], A0A_);   A0B_ = dot2f(RB_[2], W_[2], A0B_);         \
    A1A_ = dot2f(RA_[3], W_[3], A1A_);   A1B_ = dot2f(RB_[3], W_[3], A1B_);         \
    A0A_ = dot2f(RA_[4], W_[4], A0A_);   A0B_ = dot2f(RB_[4], W_[4], A0B_);         \
    A1A_ = dot2f(RA_[5], W_[5], A1A_);   A1B_ = dot2f(RB_[5], W_[5], A1B_);         \
    A0A_ = dot2f(RA_[6], W_[6], A0A_);   A0B_ = dot2f(RB_[6], W_[6], A0B_);         \
    A1A_ = dot2f(RA_[7], W_[7], A1A_);   A1B_ = dot2f(RB_[7], W_[7], A1B_);         \
    A0A_ = dot2f(RA_[8], W_[8], A0A_);   A0B_ = dot2f(RB_[8], W_[8], A0B_);         \
    A1A_ = dot2f(RA_[9], W_[9], A1A_);   A1B_ = dot2f(RB_[9], W_[9], A1B_);         \
    A0A_ = dot2f(RA_[10], W_[10], A0A_); A0B_ = dot2f(RB_[10], W_[10], A0B_);       \
    A1A_ = dot2f(RA_[11], W_[11], A1A_); A1B_ = dot2f(RB_[11], W_[11], A1B_);

#define DOT12N2(VA0,VA1,VA2, VB0,VB1,VB2, W0_,W1_,W2_, A0A_,A1A_,A0B_,A1B_)         \
    A0A_ = dot2f(VA0.x, W0_.x, A0A_); A0B_ = dot2f(VB0.x, W0_.x, A0B_);             \
    A1A_ = dot2f(VA0.y, W0_.y, A1A_); A1B_ = dot2f(VB0.y, W0_.y, A1B_);             \
    A0A_ = dot2f(VA0.z, W0_.z, A0A_); A0B_ = dot2f(VB0.z, W0_.z, A0B_);             \
    A1A_ = dot2f(VA0.w, W0_.w, A1A_); A1B_ = dot2f(VB0.w, W0_.w, A1B_);             \
    A0A_ = dot2f(VA1.x, W1_.x, A0A_); A0B_ = dot2f(VB1.x, W1_.x, A0B_);             \
    A1A_ = dot2f(VA1.y, W1_.y, A1A_); A1B_ = dot2f(VB1.y, W1_.y, A1B_);             \
    A0A_ = dot2f(VA1.z, W1_.z, A0A_); A0B_ = dot2f(VB1.z, W1_.z, A0B_);             \
    A1A_ = dot2f(VA1.w, W1_.w, A1A_); A1B_ = dot2f(VB1.w, W1_.w, A1B_);             \
    A0A_ = dot2f(VA2.x, W2_.x, A0A_); A0B_ = dot2f(VB2.x, W2_.x, A0B_);             \
    A1A_ = dot2f(VA2.y, W2_.y, A1A_); A1B_ = dot2f(VB2.y, W2_.y, A1B_);             \
    A0A_ = dot2f(VA2.z, W2_.z, A0A_); A0B_ = dot2f(VB2.z, W2_.z, A0B_);             \
    A1A_ = dot2f(VA2.w, W2_.w, A1A_); A1B_ = dot2f(VB2.w, W2_.w, A1B_);

    int RA[12], RB[12];
    GATHER(curA, RA);
    GATHER(curB, RB);

    const float* xrA = x + (size_t)bgA * T_LEN;
    const float* xrB = x + (size_t)bgB * T_LEN;
    float4 xA0, xA1, xA2, xA3, xB0, xB1, xB2, xB3;
    xA0 = xA1 = xA2 = xA3 = xB0 = xB1 = xB2 = xB3 = make_float4(0.f,0.f,0.f,0.f);
    if (l == 0) {
        const float4* a4 = (const float4*)xrA;
        const float4* b4 = (const float4*)xrB;
        xA0 = a4[0]; xA1 = a4[1]; xA2 = a4[2]; xA3 = a4[3];
        xB0 = b4[0]; xB1 = b4[1]; xB2 = b4[2]; xB3 = b4[3];
    }
#define XSEL(S, Q0, Q1, Q2, Q3)                                                     \
    ((S) == 0 ? Q0.x : (S) == 1 ? Q0.y : (S) == 2 ? Q0.z : (S) == 3 ? Q0.w          \
   : (S) == 4 ? Q1.x : (S) == 5 ? Q1.y : (S) == 6 ? Q1.z : (S) == 7 ? Q1.w          \
   : (S) == 8 ? Q2.x : (S) == 9 ? Q2.y : (S) == 10 ? Q2.z : (S) == 11 ? Q2.w        \
   : (S) == 12 ? Q3.x : (S) == 13 ? Q3.y : (S) == 14 ? Q3.z : Q3.w)

    __syncthreads();

    for (int c = 0; c < CTOT; ++c) {
        const int wp = c & 1, rp = wp ^ 1;
        if (l == 0) {
            if (c < NC) {
                float4 nA0, nA1, nA2, nA3, nB0, nB1, nB2, nB3;
                const bool pf = (c + 1 < NC);
                if (pf) {
                    const float4* a4 = (const float4*)(xrA + (size_t)(c + 1) * K);
                    const float4* b4 = (const float4*)(xrB + (size_t)(c + 1) * K);
                    nA0 = a4[0]; nA1 = a4[1]; nA2 = a4[2]; nA3 = a4[3];
                    nB0 = b4[0]; nB1 = b4[1]; nB2 = b4[2]; nB3 = b4[3];
                }
                _Float16* dA = pub0 + ((size_t)(wp * NBB + bl * 2 + 0) * K) * HID;
                _Float16* dB = pub0 + ((size_t)(wp * NBB + bl * 2 + 1) * K) * HID;
                #pragma unroll
                for (int s = 0; s < K; ++s) {
                    const float xvA = XSEL(s, xA0, xA1, xA2, xA3);
                    const float xvB = XSEL(s, xB0, xB1, xB2, xB3);
                    float a0A = fmaf(wx0, xvA, bias), a1A = 0.f;
                    float a0B = fmaf(wx0, xvB, bias), a1B = 0.f;
                    DOT12P2(RA, RB, wP, a0A, a1A, a0B, a1B);
                    curA = fmaxf(a0A + a1A, 0.f);
                    curB = fmaxf(a0B + a1B, 0.f);
                    if (act) {
                        dA[s * HID + uL] = (_Float16)curA;
                        dB[s * HID + uL] = (_Float16)curB;
                    }
                    GATHER(curA, RA);
                    GATHER(curB, RB);
                }
                if (pf) {
                    xA0 = nA0; xA1 = nA1; xA2 = nA2; xA3 = nA3;
                    xB0 = nB0; xB1 = nB1; xB2 = nB2; xB3 = nB3;
                }
            }
        } else if (l == 1) {
            if (c >= 1 && c < 1 + NC) {
                const _Float16* sA = pub0 + ((size_t)(rp * NBB + bl * 2 + 0) * K) * HID;
                const _Float16* sB = pub0 + ((size_t)(rp * NBB + bl * 2 + 1) * K) * HID;
                _Float16* dA = pub1 + ((size_t)(wp * NBB + bl * 2 + 0) * K) * HID;
                _Float16* dB = pub1 + ((size_t)(wp * NBB + bl * 2 + 1) * K) * HID;
                int4v iA0 = ((const int4v*)sA)[0], iA1 = ((const int4v*)sA)[1],
                      iA2 = ((const int4v*)sA)[2];
                int4v jA0 = ((const int4v*)sB)[0], jA1 = ((const int4v*)sB)[1],
                      jA2 = ((const int4v*)sB)[2];
                #pragma unroll
                for (int s = 0; s < K; ++s) {
                    int4v iB0, iB1, iB2, jB0, jB1, jB2;
                    if (s + 1 < K) {
                        const int4v* na = (const int4v*)(sA + (s + 1) * HID);
                        const int4v* nb = (const int4v*)(sB + (s + 1) * HID);
                        iB0 = na[0]; iB1 = na[1]; iB2 = na[2];
                        jB0 = nb[0]; jB1 = nb[1]; jB2 = nb[2];
                    }
                    float a0A = bias, a1A = 0.f, a2A = 0.f, a3A = 0.f;
                    float a0B = bias, a1B = 0.f, a2B = 0.f, a3B = 0.f;
                    DOT12N2(iA0, iA1, iA2, jA0, jA1, jA2, wiA_, wiB_, wiC_,
                            a0A, a1A, a0B, a1B);
                    DOT12P2(RA, RB, wP, a2A, a3A, a2B, a3B);
                    curA = fmaxf((a0A + a1A) + (a2A + a3A), 0.f);
                    curB = fmaxf((a0B + a1B) + (a2B + a3B), 0.f);
                    if (act) {
                        dA[s * HID + uL] = (_Float16)curA;
                        dB[s * HID + uL] = (_Float16)curB;
                    }
                    GATHER(curA, RA);
                    GATHER(curB, RB);
                    if (s + 1 < K) {
                        iA0 = iB0; iA1 = iB1; iA2 = iB2;
                        jA0 = jB0; jA1 = jB1; jA2 = jB2;
                    }
                }
            }
        } else {
            if (c >= 2 && c < 2 + NC) {
                const _Float16* sA = pub1 + ((size_t)(rp * NBB + bl * 2 + 0) * K) * HID;
                const _Float16* sB = pub1 + ((size_t)(rp * NBB + bl * 2 + 1) * K) * HID;
                int4v iA0 = ((const int4v*)sA)[0], iA1 = ((const int4v*)sA)[1],
                      iA2 = ((const int4v*)sA)[2];
                int4v jA0 = ((const int4v*)sB)[0], jA1 = ((const int4v*)sB)[1],
                      jA2 = ((const int4v*)sB)[2];
                #pragma unroll
                for (int s = 0; s < K; ++s) {
                    int4v iB0, iB1, iB2, jB0, jB1, jB2;
                    if (s + 1 < K) {
                        const int4v* na = (const int4v*)(sA + (s + 1) * HID);
                        const int4v* nb = (const int4v*)(sB + (s + 1) * HID);
                        iB0 = na[0]; iB1 = na[1]; iB2 = na[2];
                        jB0 = nb[0]; jB1 = nb[1]; jB2 = nb[2];
                    }
                    float a0A = bias, a1A = 0.f, a2A = 0.f, a3A = 0.f;
                    float a0B = bias, a1B = 0.f, a2B = 0.f, a3B = 0.f;
                    DOT12N2(iA0, iA1, iA2, jA0, jA1, jA2, wiA_, wiB_, wiC_,
                            a0A, a1A, a0B, a1B);
                    DOT12P2(RA, RB, wP, a2A, a3A, a2B, a3B);
                    curA = fmaxf((a0A + a1A) + (a2A + a3A), 0.f);
                    curB = fmaxf((a0B + a1B) + (a2B + a3B), 0.f);
                    GATHER(curA, RA);
                    GATHER(curB, RB);
                    if (s + 1 < K) {
                        iA0 = iB0; iA1 = iB1; iA2 = iB2;
                        jA0 = jB0; jA1 = jB1; jA2 = jB2;
                    }
                }
            }
        }
        __syncthreads();
    }
#undef XSEL
#undef DOT12N2
#undef DOT12P2
#undef GATHER

    if (act) {
        out[BATCH + (size_t)(l * BATCH + bgA) * HID + uL] = curA;
        out[BATCH + (size_t)(l * BATCH + bgB) * HID + uL] = curB;
    }

    if (l == 2 && act) {
        h2f[bl * 2 + 0][uL] = curA;
        h2f[bl * 2 + 1][uL] = curB;
    }
    __syncthreads();
    if (l == 2 && act) {
        const float4* w1r = (const float4*)(W1 + uL * HID);
        #pragma unroll
        for (int p = 0; p < 2; ++p) {
            const float4* hv = (const float4*)&h2f[bl * 2 + p][0];
            float a = b1[uL];
            a = dot4(w1r[0], hv[0], a); a = dot4(w1r[1], hv[1], a);
            a = dot4(w1r[2], hv[2], a); a = dot4(w1r[3], hv[3], a);
            a = dot4(w1r[4], hv[4], a); a = dot4(w1r[5], hv[5], a);
            mbuf[bl * 2 + p][uL] = fmaxf(a, 0.f);
        }
    }
    __syncthreads();
    if (l == 2 && jj == 0) {
        #pragma unroll
        for (int p = 0; p < 2; ++p) {
            float a = b2[0];
            #pragma unroll
            for (int k = 0; k < HID; ++k) a = fmaf(W2[k], mbuf[bl * 2 + p][k], a);
            out[bgA + p] = fmaxf(a, 0.f);
        }
    }
}

__global__ __launch_bounds__(TPB, 1) void rnn_ilp_kernel(
    const float* __restrict__ x, const float* __restrict__ h_in,
    const float* __restrict__ Wih0, const float* __restrict__ bih0,
    const float* __restrict__ Whh0, const float* __restrict__ bhh0,
    const float* __restrict__ Wih1, const float* __restrict__ bih1,
    const float* __restrict__ Whh1, const float* __restrict__ bhh1,
    const float* __restrict__ Wih2, const float* __restrict__ bih2,
    const float* __restrict__ Whh2, const float* __restrict__ bhh2,
    const float* __restrict__ W1,   const float* __restrict__ b1,
    const float* __restrict__ W2,   const float* __restrict__ b2,
    float* __restrict__ out)
{
    __shared__ __align__(16) _Float16 pub0[2 * NBB * K * HID];
    __shared__ __align__(16) _Float16 pub1[2 * NBB * K * HID];
    __shared__ float h2f[NBB][HID];
    __shared__ float mbuf[NBB][HID];

    const int lane = threadIdx.x & 63;
    const int d0 = __builtin_amdgcn_readfirstlane(rr<2>(lane));
    const int dir = (d0 == 2) ? 1 : -1;

#if __has_builtin(__builtin_amdgcn_permlane16_swap)
    uint2v sw = __builtin_amdgcn_permlane16_swap((unsigned)lane, (unsigned)lane,
                                                 false, false);
    const int s0  = __builtin_amdgcn_readlane((int)sw.x, 0);
    const int s16 = __builtin_amdgcn_readlane((int)sw.x, 16);
    const bool ok   = (s0 == 0 && s16 == 0) || (s0 == 16 && s16 == 16);
    const bool flip = (s0 == 16);
    if (ok) {
        run_rnn<false>(x, h_in, Wih0, bih0, Whh0, bhh0, Wih1, bih1, Whh1, bhh1,
                       Wih2, bih2, Whh2, bhh2, W1, b1, W2, b2, out,
                       dir, flip, pub0, pub1, h2f, mbuf);
    } else {
        run_rnn<true>(x, h_in, Wih0, bih0, Whh0, bhh0, Wih1, bih1, Whh1, bhh1,
                      Wih2, bih2, Whh2, bhh2, W1, b1, W2, b2, out,
                      dir, false, pub0, pub1, h2f, mbuf);
    }
#else
    run_rnn<true>(x, h_in, Wih0, bih0, Whh0, bhh0, Wih1, bih1, Whh1, bhh1,
                  Wih2, bih2, Whh2, bhh2, W1, b1, W2, b2, out,
                  dir, false, pub0, pub1, h2f, mbuf);
#endif
}

extern "C" void kernel_launch(void* const* d_in, const int* in_sizes, int n_in,
                              void* d_out, int out_size, void* d_ws, size_t ws_size,
                              hipStream_t stream) {
    const float* x    = (const float*)d_in[0];
    const float* h_in = (const float*)d_in[1];
    const float* Wih0 = (const float*)d_in[2];
    const float* bih0 = (const float*)d_in[3];
    const float* Whh0 = (const float*)d_in[4];
    const float* bhh0 = (const float*)d_in[5];
    const float* Wih1 = (const float*)d_in[6];
    const float* bih1 = (const float*)d_in[7];
    const float* Whh1 = (const float*)d_in[8];
    const float* bhh1 = (const float*)d_in[9];
    const float* Wih2 = (const float*)d_in[10];
    const float* bih2 = (const float*)d_in[11];
    const float* Whh2 = (const float*)d_in[12];
    const float* bhh2 = (const float*)d_in[13];
    const float* W1   = (const float*)d_in[14];
    const float* b1   = (const float*)d_in[15];
    const float* W2   = (const float*)d_in[16];
    const float* b2   = (const float*)d_in[17];
    float* out = (float*)d_out;

    dim3 grid(BATCH / NBB);   // 256 blocks -> 1 block/CU, 1 wave/SIMD (VGPR-free)
    dim3 block(TPB);          // 3 waves (wave == layer), 2 batches per lane
    hipLaunchKernelGGL(rnn_ilp_kernel, grid, block, 0, stream,
                       x, h_in, Wih0, bih0, Whh0, bhh0,
                       Wih1, bih1, Whh1, bhh1, Wih2, bih2, Whh2, bhh2,
                       W1, b1, W2, b2, out);
}

// Round 13
// 892.051 us; speedup vs baseline: 1.0851x; 1.0851x over previous
//
#include <hip/hip_runtime.h>

#define HID   24
#define T_LEN 4096
#define BATCH 1024
#define NB    2                  // batches per block (one per 32-lane half)
#define K     16                 // timesteps per chunk (pipeline skew per layer)
#define NC    (T_LEN / K)        // 256 active chunks per layer
#define CTOT  (NC + 2)           // 258 ticks (3-layer skew)
#define TPB   192                // 3 waves: wave w == layer w

typedef __attribute__((ext_vector_type(2))) _Float16 h2v;
typedef __attribute__((ext_vector_type(4))) int      int4v;

#if __has_builtin(__builtin_amdgcn_fdot2)
__device__ __forceinline__ float dot2f(int p, int w, float acc) {
    return __builtin_amdgcn_fdot2(__builtin_bit_cast(h2v, p),
                                  __builtin_bit_cast(h2v, w), acc, false);
}
#else
__device__ __forceinline__ float dot2f(int p, int w, float acc) {
    h2v a = __builtin_bit_cast(h2v, p), b = __builtin_bit_cast(h2v, w);
    acc = fmaf((float)a.x, (float)b.x, acc);
    return fmaf((float)a.y, (float)b.y, acc);
}
#endif

__device__ __forceinline__ float dot4(const float4 a, const float4 b, float acc) {
    acc = fmaf(a.x, b.x, acc);
    acc = fmaf(a.y, b.y, acc);
    acc = fmaf(a.z, b.z, acc);
    return fmaf(a.w, b.w, acc);
}

// DPP row-rotate by N within 16-lane rows (VALU pipe) — validated r10/r11
template<int N> __device__ __forceinline__ int rr(int v) {
    return __builtin_amdgcn_mov_dpp(v, 0x120 + N, 0xF, 0xF, false);
}
// quad_perm [1,0,3,2]: neighbor swap within pairs — validated r10/r11
__device__ __forceinline__ int qp_nbr(int v) {
    return __builtin_amdgcn_mov_dpp(v, 0xB1, 0xF, 0xF, false);
}

// pack two f32 -> packed f16 pair dword (natural order)
#define PKF(A_, B_)                                                                 \
    (((int)__builtin_bit_cast(unsigned short, (_Float16)(B_)) << 16) |              \
     (int)__builtin_bit_cast(unsigned short, (_Float16)(A_)))

// weight pair for rotation slot m: source pair follows rr<2m> of own 16-row
__device__ __forceinline__ int pkw_rot(const float* Wrow, int lane, int dir,
                                       int m, int kbase) {
    const int s = ((lane & 15) + dir * (2 * m)) & 15;
    const int k = kbase + 2 * (s >> 1);
    float wl = (k < HID)     ? Wrow[k]     : 0.f;
    float wh = (k + 1 < HID) ? Wrow[k + 1] : 0.f;
    if (lane & 1) { float t = wl; wl = wh; wh = t; }   // odd lanes see swapped halves
    return PKF(wl, wh);
}

__global__ __launch_bounds__(TPB, 1) void rnn_rot_kernel(
    const float* __restrict__ x,     // [B, T]
    const float* __restrict__ h_in,  // [3, B, 24]
    const float* __restrict__ Wih0, const float* __restrict__ bih0,
    const float* __restrict__ Whh0, const float* __restrict__ bhh0,
    const float* __restrict__ Wih1, const float* __restrict__ bih1,
    const float* __restrict__ Whh1, const float* __restrict__ bhh1,
    const float* __restrict__ Wih2, const float* __restrict__ bih2,
    const float* __restrict__ Whh2, const float* __restrict__ bhh2,
    const float* __restrict__ W1,   const float* __restrict__ b1,
    const float* __restrict__ W2,   const float* __restrict__ b2,
    float* __restrict__ out)         // [1024 (y)] ++ [3*1024*24 (h_final)]
{
    // inter-layer publication rows only (own-h lives in registers now)
    __shared__ __align__(16) _Float16 pub0[2 * NB * K * HID];
    __shared__ __align__(16) _Float16 pub1[2 * NB * K * HID];
    __shared__ float h2f[NB][HID];
    __shared__ float mbuf[NB][HID];

    const int tid  = threadIdx.x;
    const int l    = tid >> 6;        // wave == layer
    const int lane = tid & 63;
    const int bl   = lane >> 5;       // batch half
    const int jj   = lane & 31;
    const bool act = (jj < HID);
    const int uL   = act ? jj : (jj - 8);     // lanes 24-31 duplicate units 16-23
    const int row1 = (jj >> 4) & 1;           // 16-lane row within the 32-half
    const int kbase = row1 * 16;              // own-row k range
    // partner unit (lane ^ 16 within the 32-half)
    const int up = (jj < 16) ? ((jj + 16 < HID) ? jj + 16 : jj + 8) : (jj - 16);
    const int bg = blockIdx.x * NB + bl;

    // probe DPP row_ror direction (wave-uniform)
    const int d0 = __builtin_amdgcn_readfirstlane(rr<2>(lane));
    const int dir = (d0 == 2) ? 1 : -1;

    // ---- own-h weights in rotation order: A = my unit's row, B = partner's row ----
    const float* Wown = (l == 0) ? Whh0 : (l == 1) ? Whh1 : Whh2;
    int wA0, wA1, wA2, wA3, wA4, wA5, wA6, wA7;
    int wB0, wB1, wB2, wB3, wB4, wB5, wB6, wB7;
    {
        const float* rA = Wown + uL * HID;
        const float* rB = Wown + up * HID;
        wA0 = pkw_rot(rA, lane, dir, 0, kbase); wB0 = pkw_rot(rB, lane, dir, 0, kbase);
        wA1 = pkw_rot(rA, lane, dir, 1, kbase); wB1 = pkw_rot(rB, lane, dir, 1, kbase);
        wA2 = pkw_rot(rA, lane, dir, 2, kbase); wB2 = pkw_rot(rB, lane, dir, 2, kbase);
        wA3 = pkw_rot(rA, lane, dir, 3, kbase); wB3 = pkw_rot(rB, lane, dir, 3, kbase);
        wA4 = pkw_rot(rA, lane, dir, 4, kbase); wB4 = pkw_rot(rB, lane, dir, 4, kbase);
        wA5 = pkw_rot(rA, lane, dir, 5, kbase); wB5 = pkw_rot(rB, lane, dir, 5, kbase);
        wA6 = pkw_rot(rA, lane, dir, 6, kbase); wB6 = pkw_rot(rB, lane, dir, 6, kbase);
        wA7 = pkw_rot(rA, lane, dir, 7, kbase); wB7 = pkw_rot(rB, lane, dir, 7, kbase);
    }
    // ---- input-from-below weights, natural packed order (layers 1,2) ----
    int4v wiA = {0,0,0,0}, wiB = {0,0,0,0}, wiC = {0,0,0,0};
    if (l >= 1) {
        const float* r_ = ((l == 1) ? Wih1 : Wih2) + uL * HID;
        wiA = (int4v){PKF(r_[0], r_[1]),   PKF(r_[2], r_[3]),
                      PKF(r_[4], r_[5]),   PKF(r_[6], r_[7])};
        wiB = (int4v){PKF(r_[8], r_[9]),   PKF(r_[10], r_[11]),
                      PKF(r_[12], r_[13]), PKF(r_[14], r_[15])};
        wiC = (int4v){PKF(r_[16], r_[17]), PKF(r_[18], r_[19]),
                      PKF(r_[20], r_[21]), PKF(r_[22], r_[23])};
    }
    const float wx0  = Wih0[uL];
    const float bias = (l == 0) ? (bih0[uL] + bhh0[uL])
                     : (l == 1) ? (bih1[uL] + bhh1[uL])
                                : (bih2[uL] + bhh2[uL]);

    float cur = h_in[(l * BATCH + bg) * HID + uL];

    // rotation register set: 8 pair-dwords of own-row h (pads packed as zero)
    int R0, R1, R2, R3, R4, R5, R6, R7;
#define REBUILD() do {                                                              \
        int hc_ = act ? (int)(unsigned)__builtin_bit_cast(unsigned short,           \
                                                          (_Float16)cur) : 0;      \
        int pk_ = (qp_nbr(hc_) << 16) | hc_;                                        \
        R0 = pk_;       R1 = rr<2>(pk_);  R2 = rr<4>(pk_);  R3 = rr<6>(pk_);        \
        R4 = rr<8>(pk_); R5 = rr<10>(pk_); R6 = rr<12>(pk_); R7 = rr<14>(pk_);      \
    } while (0)
    REBUILD();

// own-dot: A partial (my unit) + B partial (partner unit), then xor-16 swizzle
#define OWNDOT(TOT_BASE_, RES_) do {                                                \
        float aA0 = 0.f, aA1 = 0.f, aB0 = 0.f, aB1 = 0.f;                           \
        aA0 = dot2f(R0, wA0, aA0); aA1 = dot2f(R1, wA1, aA1);                       \
        aB0 = dot2f(R0, wB0, aB0); aB1 = dot2f(R1, wB1, aB1);                       \
        aA0 = dot2f(R2, wA2, aA0); aA1 = dot2f(R3, wA3, aA1);                       \
        aB0 = dot2f(R2, wB2, aB0); aB1 = dot2f(R3, wB3, aB1);                       \
        aA0 = dot2f(R4, wA4, aA0); aA1 = dot2f(R5, wA5, aA1);                       \
        aB0 = dot2f(R4, wB4, aB0); aB1 = dot2f(R5, wB5, aB1);                       \
        aA0 = dot2f(R6, wA6, aA0); aA1 = dot2f(R7, wA7, aA1);                       \
        aB0 = dot2f(R6, wB6, aB0); aB1 = dot2f(R7, wB7, aB1);                       \
        const float Bsum_ = aB0 + aB1;                                              \
        const int   Bswz_ = __builtin_amdgcn_ds_swizzle(__float_as_int(Bsum_),      \
                                                        0x401F);                    \
        RES_ = (TOT_BASE_) + (aA0 + aA1) + __int_as_float(Bswz_);                   \
    } while (0)

#define DOT12N(V0_, V1_, V2_, A0_, A1_)                                             \
    A0_ = dot2f(V0_.x, wiA.x, A0_); A1_ = dot2f(V0_.y, wiA.y, A1_);                 \
    A0_ = dot2f(V0_.z, wiA.z, A0_); A1_ = dot2f(V0_.w, wiA.w, A1_);                 \
    A0_ = dot2f(V1_.x, wiB.x, A0_); A1_ = dot2f(V1_.y, wiB.y, A1_);                 \
    A0_ = dot2f(V1_.z, wiB.z, A0_); A1_ = dot2f(V1_.w, wiB.w, A1_);                 \
    A0_ = dot2f(V2_.x, wiC.x, A0_); A1_ = dot2f(V2_.y, wiC.y, A1_);                 \
    A0_ = dot2f(V2_.z, wiC.z, A0_); A1_ = dot2f(V2_.w, wiC.w, A1_);

    // x quads in registers (layer-0 wave)
    const float* xrow = x + (size_t)bg * T_LEN;
    float4 xq0, xq1, xq2, xq3;
    xq0 = xq1 = xq2 = xq3 = make_float4(0.f, 0.f, 0.f, 0.f);
    if (l == 0) {
        const float4* xr = (const float4*)xrow;
        xq0 = xr[0]; xq1 = xr[1]; xq2 = xr[2]; xq3 = xr[3];
    }
#define XV(S)                                                                       \
    ((S) == 0 ? xq0.x : (S) == 1 ? xq0.y : (S) == 2 ? xq0.z : (S) == 3 ? xq0.w      \
   : (S) == 4 ? xq1.x : (S) == 5 ? xq1.y : (S) == 6 ? xq1.z : (S) == 7 ? xq1.w      \
   : (S) == 8 ? xq2.x : (S) == 9 ? xq2.y : (S) == 10 ? xq2.z : (S) == 11 ? xq2.w    \
   : (S) == 12 ? xq3.x : (S) == 13 ? xq3.y : (S) == 14 ? xq3.z : xq3.w)

    __syncthreads();

    // ---- chunked, layer-skewed scan: tick c, layer l handles t in [(c-l)*K, +K) ----
    for (int c = 0; c < CTOT; ++c) {
        const int wp = c & 1, rp = wp ^ 1;
        if (l == 0) {
            if (c < NC) {
                float4 xn0, xn1, xn2, xn3;
                const bool pf = (c + 1 < NC);
                if (pf) {
                    const float4* xn = (const float4*)(xrow + (size_t)(c + 1) * K);
                    xn0 = xn[0]; xn1 = xn[1]; xn2 = xn[2]; xn3 = xn[3];
                }
                _Float16* dst = pub0 + ((size_t)(wp * NB + bl) * K) * HID;
                #pragma unroll
                for (int s = 0; s < K; ++s) {
                    float tot;
                    OWNDOT(fmaf(wx0, XV(s), bias), tot);
                    cur = fmaxf(tot, 0.f);
                    if (act) dst[s * HID + uL] = (_Float16)cur;
                    REBUILD();
                }
                if (pf) { xq0 = xn0; xq1 = xn1; xq2 = xn2; xq3 = xn3; }
            }
        } else if (l == 1) {
            if (c >= 1 && c < 1 + NC) {
                const _Float16* src = pub0 + ((size_t)(rp * NB + bl) * K) * HID;
                _Float16* dst = pub1 + ((size_t)(wp * NB + bl) * K) * HID;
                int4v iA0 = ((const int4v*)src)[0];
                int4v iA1 = ((const int4v*)src)[1];
                int4v iA2 = ((const int4v*)src)[2];
                #pragma unroll
                for (int s = 0; s < K; ++s) {
                    int4v iB0, iB1, iB2;
                    if (s + 1 < K) {
                        const int4v* nr = (const int4v*)(src + (s + 1) * HID);
                        iB0 = nr[0]; iB1 = nr[1]; iB2 = nr[2];
                    }
                    float a0 = bias, a1 = 0.f;
                    DOT12N(iA0, iA1, iA2, a0, a1);
                    float tot;
                    OWNDOT(a0 + a1, tot);
                    cur = fmaxf(tot, 0.f);
                    if (act) dst[s * HID + uL] = (_Float16)cur;
                    REBUILD();
                    if (s + 1 < K) { iA0 = iB0; iA1 = iB1; iA2 = iB2; }
                }
            }
        } else {
            if (c >= 2 && c < 2 + NC) {
                const _Float16* src = pub1 + ((size_t)(rp * NB + bl) * K) * HID;
                int4v iA0 = ((const int4v*)src)[0];
                int4v iA1 = ((const int4v*)src)[1];
                int4v iA2 = ((const int4v*)src)[2];
                #pragma unroll
                for (int s = 0; s < K; ++s) {
                    int4v iB0, iB1, iB2;
                    if (s + 1 < K) {
                        const int4v* nr = (const int4v*)(src + (s + 1) * HID);
                        iB0 = nr[0]; iB1 = nr[1]; iB2 = nr[2];
                    }
                    float a0 = bias, a1 = 0.f;
                    DOT12N(iA0, iA1, iA2, a0, a1);
                    float tot;
                    OWNDOT(a0 + a1, tot);
                    cur = fmaxf(tot, 0.f);
                    REBUILD();
                    if (s + 1 < K) { iA0 = iB0; iA1 = iB1; iA2 = iB2; }
                }
            }
        }
        __syncthreads();
    }
#undef XV
#undef DOT12N
#undef OWNDOT
#undef REBUILD

    // ---- h_final from the f32 running value ----
    if (act) out[BATCH + (size_t)(l * BATCH + bg) * HID + uL] = cur;

    // ---- MLP head on h2(T-1) ----
    if (l == 2 && act) h2f[bl][uL] = cur;
    __syncthreads();
    if (l == 2 && act) {
        const float4* w1r = (const float4*)(W1 + uL * HID);
        const float4* hv  = (const float4*)&h2f[bl][0];
        float a = b1[uL];
        a = dot4(w1r[0], hv[0], a); a = dot4(w1r[1], hv[1], a);
        a = dot4(w1r[2], hv[2], a); a = dot4(w1r[3], hv[3], a);
        a = dot4(w1r[4], hv[4], a); a = dot4(w1r[5], hv[5], a);
        mbuf[bl][uL] = fmaxf(a, 0.f);
    }
    __syncthreads();
    if (l == 2 && jj == 0) {
        float a = b2[0];
        #pragma unroll
        for (int k = 0; k < HID; ++k) a = fmaf(W2[k], mbuf[bl][k], a);
        out[bg] = fmaxf(a, 0.f);
    }
}

extern "C" void kernel_launch(void* const* d_in, const int* in_sizes, int n_in,
                              void* d_out, int out_size, void* d_ws, size_t ws_size,
                              hipStream_t stream) {
    const float* x    = (const float*)d_in[0];
    const float* h_in = (const float*)d_in[1];
    const float* Wih0 = (const float*)d_in[2];
    const float* bih0 = (const float*)d_in[3];
    const float* Whh0 = (const float*)d_in[4];
    const float* bhh0 = (const float*)d_in[5];
    const float* Wih1 = (const float*)d_in[6];
    const float* bih1 = (const float*)d_in[7];
    const float* Whh1 = (const float*)d_in[8];
    const float* bhh1 = (const float*)d_in[9];
    const float* Wih2 = (const float*)d_in[10];
    const float* bih2 = (const float*)d_in[11];
    const float* Whh2 = (const float*)d_in[12];
    const float* bhh2 = (const float*)d_in[13];
    const float* W1   = (const float*)d_in[14];
    const float* b1   = (const float*)d_in[15];
    const float* W2   = (const float*)d_in[16];
    const float* b2   = (const float*)d_in[17];
    float* out = (float*)d_out;

    dim3 grid(BATCH / NB);   // 512 blocks -> 2 blocks/CU, 6 waves/CU
    dim3 block(TPB);         // 3 waves (wave == layer)
    hipLaunchKernelGGL(rnn_rot_kernel, grid, block, 0, stream,
                       x, h_in, Wih0, bih0, Whh0, bhh0,
                       Wih1, bih1, Whh1, bhh1, Wih2, bih2, Whh2, bhh2,
                       W1, b1, W2, b2, out);
}